// Round 16
// baseline (437.875 us; speedup 1.0000x reference)
//
#include <hip/hip_runtime.h>
#include <hip/hip_bf16.h>

typedef __hip_bfloat16 bf16;
typedef float v2f __attribute__((ext_vector_type(2)));

#define LEN 1024
#define N2 2048            // B * L rows
#define SCALE_L2E 0.5100697918f   // (1/sqrt(8)) * log2(e)

// ---- converted-input float offsets in ws ----
#define I_SCTX   0
#define I_FCTX   4096
#define I_STEST  6144
#define I_OBS    10240
#define I_EW1    10248
#define I_EB1    12040
#define I_EW2    12296
#define I_EB2    28680
#define I_WQ     28744
#define I_BQ     53320
#define I_WK     53704
#define I_BK     78280
#define I_WV     78664
#define I_BV     103240
#define I_WO     103624
#define I_BO     128200
#define I_FW1    128584
#define I_FB1    177736
#define I_FW2    178504
#define I_FB2    227656
#define I_BW1    228040
#define I_BB1    228136
#define I_BW2    228232
#define I_BB2    229000
#define I_NS     229048
#define I_NB     229432
#define I_FNS    229816
#define I_FNB    229880
#define I_HW1    229944
#define I_HB1    238136
#define I_HW2    238264
#define I_HB2    238520

#define OFF_FLAG 240000
#define OFF_PW   240256    // 6 layers x 288 floats: [17][8] (slope,inter)*log2e + 16 sorted bps
#define OFF_QVS  262144
#define OFF_KVS  393216
#define OFF_Q1   524288
#define OFF_Q2   655360
#define OFF_KB   786432
#define OFF_VB   917504
#define OFF_PART 1048576   // partials: [z=4][row=1024][h=8][ks=8][12] floats (row stride 768)

__constant__ int C_OFFS[33] = {
    0, 4096, 6144, 10240, 10248, 12040, 12296, 28680, 28744, 53320, 53704,
    78280, 78664, 103240, 103624, 128200, 128584, 177736, 178504, 227656,
    228040, 228136, 228232, 229000, 229048, 229432, 229816, 229880, 229944,
    238136, 238264, 238520, 238522 };

struct InPtrs { const void* p[32]; };

__device__ __forceinline__ int get_isbf(const void* ns) {
    return (*(const unsigned*)ns == 0x3F803F80u) ? 1 : 0;
}

// ---- merged prologue: input conversion (blocks 0..255) + flag + piecewise
// bias tables (blocks 256..261). pwf reads raw inputs -> no ordering dep.
__global__ __launch_bounds__(256) void k_pre(InPtrs ptrs, float* ws) {
    const int bid = blockIdx.x, t = threadIdx.x;
    const int isbf = get_isbf(ptrs.p[24]);
    if (bid < 256) {
        const int i = bid & 31, sub = bid >> 5;
        const int o0 = C_OFFS[i], n = C_OFFS[i + 1] - o0;
        const void* src = ptrs.p[i];
        for (int j = sub * 256 + t; j < n; j += 8 * 256) {
            float v = isbf ? __bfloat162float(((const bf16*)src)[j])
                           : ((const float*)src)[j];
            ws[o0 + j] = v;
        }
        return;
    }
    // ---- piecewise tables for layer L ----
    const int L = bid - 256;
    __shared__ float w1s[16], b1s[16], bps[16];
    __shared__ int rnk[16];
    auto cv = [&](const void* p, int idx) -> float {
        return isbf ? __bfloat162float(((const bf16*)p)[idx]) : ((const float*)p)[idx];
    };
    if (t == 0 && L == 0) ((int*)(ws + OFF_FLAG))[0] = isbf;
    if (t < 16) {
        float w = cv(ptrs.p[20], L * 16 + t), b0 = cv(ptrs.p[21], L * 16 + t);
        w1s[t] = w; b1s[t] = b0;
        bps[t] = (w != 0.f) ? (-b0 / w) : 1e30f;
    }
    __syncthreads();
    if (t < 16) {
        float me = bps[t]; int r = 0;
        for (int j = 0; j < 16; ++j) {
            float o = bps[j];
            if (o < me || (o == me && j < t)) ++r;
        }
        rnk[t] = r;
    }
    __syncthreads();
    if (t < 16) ws[OFF_PW + L * 288 + 272 + rnk[t]] = bps[t];
    if (t < 136) {
        int s = t >> 3, h = t & 7;
        float slope = 0.f, inter = cv(ptrs.p[23], L * 8 + h);
        for (int j = 0; j < 16; ++j) {
            float w = w1s[j];
            bool act = (w > 0.f) ? (rnk[j] < s)
                     : (w < 0.f) ? (rnk[j] >= s)
                                 : (b1s[j] > 0.f);
            if (act) {
                float w2v = cv(ptrs.p[22], L * 128 + j * 8 + h);
                slope += w * w2v;
                inter += b1s[j] * w2v;
            }
        }
        const float LOG2E = 1.4426950408889634f;
        ws[OFF_PW + L * 288 + (s * 8 + h) * 2]     = slope * LOG2E;
        ws[OFF_PW + L * 288 + (s * 8 + h) * 2 + 1] = inter * LOG2E;
    }
}

// ---- merged embed MLP + layer-0 QKV; 2 rows per block (4 MLP instances
// share every weight read). grid 1024 x 256. Per-row math order unchanged.
__global__ __launch_bounds__(256) void k_emq(float* ws) {
    __shared__ float hbuf[4][256];    // c = lr*2 + which (0=ctx, 1=test)
    __shared__ float red[4][256];
    __shared__ float xs[4][64];
    const int r0 = blockIdx.x * 2, t = threadIdx.x;

    float in_[4][7];
#pragma unroll
    for (int lr = 0; lr < 2; ++lr) {
        int r = r0 + lr;
        const float* obc = ws + I_OBS + 4;
        const float* obu = ws + I_OBS;
        float* ic = in_[lr * 2]; float* it = in_[lr * 2 + 1];
        ic[0] = obc[0]; ic[1] = obc[1]; ic[2] = obc[2]; ic[3] = obc[3];
        it[0] = obu[0]; it[1] = obu[1]; it[2] = obu[2]; it[3] = obu[3];
        ic[4] = ws[I_SCTX + r * 2]; ic[5] = ws[I_SCTX + r * 2 + 1];
        it[4] = ws[I_STEST + r * 2]; it[5] = ws[I_STEST + r * 2 + 1];
        ic[6] = ws[I_FCTX + r]; it[6] = 0.f;
    }
    float a[4];
    {
        float b1v = ws[I_EB1 + t];
        a[0] = a[1] = a[2] = a[3] = b1v;
    }
#pragma unroll
    for (int i = 0; i < 7; ++i) {
        float w = ws[I_EW1 + i * 256 + t];
#pragma unroll
        for (int c = 0; c < 4; ++c) a[c] += in_[c][i] * w;
    }
#pragma unroll
    for (int c = 0; c < 4; ++c) hbuf[c][t] = fmaxf(a[c], 0.f);
    __syncthreads();

    {
        int d = t & 63, p = t >> 6;
        float s2[4] = {0.f, 0.f, 0.f, 0.f};
#pragma unroll 8
        for (int j = p * 64; j < p * 64 + 64; ++j) {
            float w = ws[I_EW2 + j * 64 + d];
#pragma unroll
            for (int c = 0; c < 4; ++c) s2[c] += hbuf[c][j] * w;
        }
#pragma unroll
        for (int c = 0; c < 4; ++c) red[c][t] = s2[c];
    }
    __syncthreads();
    {
        int c = t >> 6, d2 = t & 63;
        float o = red[c][d2] + red[c][64 + d2] + red[c][128 + d2]
                + red[c][192 + d2] + ws[I_EB2 + d2];
        int lr = c >> 1, which = c & 1; int r = r0 + lr;
        if (which == 0) ws[OFF_KVS + r * 64 + d2] = o;
        else            ws[OFF_QVS + r * 64 + d2] = o;
        xs[c][d2] = o;
    }
    __syncthreads();

    // layer-0 QKV: wave o4: 0=Q1(test), 1=Q2(ctx), 2=KB(ctx), 3=VB(ctx);
    // each wave projects BOTH rows (weight read shared 2x)
    {
        int o4 = t >> 6, d = t & 63;
        const float* W; const float* bbp; float* dst; int whichx;
        if (o4 == 0)      { W = ws + I_WQ; bbp = ws + I_BQ; dst = ws + OFF_Q1; whichx = 1; }
        else if (o4 == 1) { W = ws + I_WQ; bbp = ws + I_BQ; dst = ws + OFF_Q2; whichx = 0; }
        else if (o4 == 2) { W = ws + I_WK; bbp = ws + I_BK; dst = ws + OFF_KB; whichx = 0; }
        else              { W = ws + I_WV; bbp = ws + I_BV; dst = ws + OFF_VB; whichx = 0; }
        float a0 = bbp[d], a1 = a0;
#pragma unroll 8
        for (int k = 0; k < 64; ++k) {
            float w = W[k * 64 + d];
            a0 += xs[whichx][k] * w;
            a1 += xs[2 + whichx][k] * w;
        }
        dst[r0 * 64 + d]       = a0;
        dst[(r0 + 1) * 64 + d] = a1;
    }
}

// ---- attention: wave-private tiles, NO per-tile barriers (R13/R15 best) ----
// NEW vs R15: pw table row stride padded 16 -> 20 floats (80 B, float4-legal).
// With stride 16 (64 B) all 17 segment rows started at bank 0 or 16, so the
// 4 b128 pw reads at data-dependent s0 serialized up to ~9-way (the 2.35M
// SQ_LDS_BANK_CONFLICT source). Stride 20 gives 8 distinct row-start banks.
// LDS 18512 B x 8 blocks = 148 KB <= 160 -> occupancy unchanged. Arithmetic
// identical -> absmax bit-identical.
// grid (qt=64, ks=8, z=4); launch bounds (256,4) (proven: forcing 8 waves/EU
// collapses the allocator to 32 VGPR + 394 MB spill).
__global__ __launch_bounds__(256, 4) void k_attn(int blk, float* ws) {
    __shared__ float smem[4628];            // 18512 B
    float* Ks  = smem;                      // 16 x 68
    float* Vs  = smem + 1088;               // 16 x 68
    float* bbf = smem + 2176;               // bias [16][132] = 2112
    float* pw  = smem + 4288;               // 17 rows x 20 floats (16 used + 4 pad)

    const int t = threadIdx.x;
    const int qt = blockIdx.x, ks = blockIdx.y, z = blockIdx.z;
    const int b = z & 1, kind = z >> 1;
    const int q0 = qt * 16;
    const float* Qbuf = ws + (kind == 0 ? OFF_Q1 : OFF_Q2);
    const float* Kbuf = ws + OFF_KB;
    const float* Vbuf = ws + OFF_VB;
    const float* sq_src = ws + (kind == 0 ? I_STEST : I_SCTX);
    const float* sk_src = ws + I_SCTX;
    const float* pwg = ws + OFF_PW + blk * 288;   // uniform -> scalar loads

    float bp[16];
#pragma unroll
    for (int j = 0; j < 16; ++j) bp[j] = pwg[272 + j];

    if (t < 136) {
        int s = t >> 3, j = (t & 7) * 2;
        pw[s * 20 + j]     = pwg[t * 2];
        pw[s * 20 + j + 1] = pwg[t * 2 + 1];
    }

    const int h    = t & 7;         // head (inner loop)
    const int qg   = (t >> 3) & 7;  // query pair (qg*2, qg*2+1) (inner loop)
    const int ksub = t >> 6;        // wave id == key quartet [4*ksub, +4)

    // Q fragments for 2 queries, resident in registers
    v2f qf[2][4];
#pragma unroll
    for (int qq = 0; qq < 2; ++qq) {
        const float* qp = Qbuf + (b * LEN + q0 + qg * 2 + qq) * 64 + h * 8;
        float4 qa = *(const float4*)qp;
        float4 qb = *(const float4*)(qp + 4);
        qf[qq][0] = (v2f){qa.x, qa.y}; qf[qq][1] = (v2f){qa.z, qa.w};
        qf[qq][2] = (v2f){qb.x, qb.y}; qf[qq][3] = (v2f){qb.z, qb.w};
    }
    // bias-phase coords: this thread handles (k = 4*ksub + (t&3), q = (t>>2)&15)
    const int kp = ksub * 4 + (t & 3);      // key row (wave-private quartet)
    const int qs = (t >> 2) & 15;           // query for bias
    float sqx, sqy;
    {
        const float* sp = sq_src + (b * LEN + q0 + qs) * 2;
        sqx = sp[0]; sqy = sp[1];
    }

    float lsum[2] = {0.f, 0.f};
    v2f oacc[2][4] = {};

    const int kt0 = ks * 8, kt1 = kt0 + 8;   // tiles of 16 keys
    const int kr = t >> 4, jc = (t & 15) * 4;   // staging coords (kr in-wave)

    // prologue: prefetch tile kt0 (K/V fragments AND key coords)
    float4 ka, va;
    float2 kc_pf;
    {
        const float* ksrc = Kbuf + (b * LEN + kt0 * 16 + kr) * 64 + jc;
        const float* vsrc = Vbuf + (b * LEN + kt0 * 16 + kr) * 64 + jc;
        ka = *(const float4*)ksrc;
        va = *(const float4*)vsrc;
        kc_pf = *(const float2*)(sk_src + (b * LEN + kt0 * 16 + kp) * 2);
    }

    __syncthreads();                  // pw table visible to all waves

    for (int kt = kt0; kt < kt1; ++kt) {
        // stage this wave's K/V rows (within-wave write->read only)
        *(float4*)&Ks[kr * 68 + jc] = ka;
        *(float4*)&Vs[kr * 68 + jc] = va;
        {   // bias precompute for wave-private keys: (kp, qs) pair
            float dx0 = sqx - kc_pf.x, dy0 = sqy - kc_pf.y;
            float d0 = dx0 * dx0 + dy0 * dy0;
            int s0 = 0;
#pragma unroll
            for (int j = 0; j < 16; ++j) s0 += (d0 > bp[j]);
            const float* p0 = pw + s0 * 20;   // 16 floats: sl,in x8 (stride-20 row)
            float* bd0 = &bbf[kp * 132 + qs * 8];
            float4 a0 = *(const float4*)p0,       a1 = *(const float4*)(p0 + 4);
            float4 a2 = *(const float4*)(p0 + 8), a3 = *(const float4*)(p0 + 12);
            *(float4*)bd0       = make_float4(fmaf(a0.x, d0, a0.y), fmaf(a0.z, d0, a0.w),
                                              fmaf(a1.x, d0, a1.y), fmaf(a1.z, d0, a1.w));
            *(float4*)(bd0 + 4) = make_float4(fmaf(a2.x, d0, a2.y), fmaf(a2.z, d0, a2.w),
                                              fmaf(a3.x, d0, a3.y), fmaf(a3.z, d0, a3.w));
        }

        // prefetch next tile (K/V + kc; latency hides under compute below)
        if (kt + 1 < kt1) {
            const float* ksrc = Kbuf + (b * LEN + (kt + 1) * 16 + kr) * 64 + jc;
            const float* vsrc = Vbuf + (b * LEN + (kt + 1) * 16 + kr) * 64 + jc;
            ka = *(const float4*)ksrc;
            va = *(const float4*)vsrc;
            kc_pf = *(const float2*)(sk_src + (b * LEN + (kt + 1) * 16 + kp) * 2);
        }

        // inner: 4 wave-private keys; K/V frags broadcast 8-way, 2 queries each
        const float* Kb = &Ks[(ksub * 4) * 68 + h * 8];
        const float* Vb = &Vs[(ksub * 4) * 68 + h * 8];
        const float* Bb = &bbf[(ksub * 4) * 132 + qg * 16 + h];
#pragma unroll
        for (int k4 = 0; k4 < 4; ++k4) {
            const v2f* kf = (const v2f*)(Kb + k4 * 68);
            v2f k0 = kf[0], k1 = kf[1], k2v = kf[2], k3 = kf[3];
            const v2f* vf = (const v2f*)(Vb + k4 * 68);
            v2f v0 = vf[0], v1 = vf[1], v2v = vf[2], v3 = vf[3];
#pragma unroll
            for (int qq = 0; qq < 2; ++qq) {
                float bv = Bb[k4 * 132 + qq * 8];
                v2f a = qf[qq][0] * k0;
                a += qf[qq][1] * k1;
                a += qf[qq][2] * k2v;
                a += qf[qq][3] * k3;
                float sv = fmaf(a.x + a.y, SCALE_L2E, bv);
                float p = exp2f(sv);
                lsum[qq] += p;
                v2f pp = (v2f){p, p};
                oacc[qq][0] += pp * v0;
                oacc[qq][1] += pp * v1;
                oacc[qq][2] += pp * v2v;
                oacc[qq][3] += pp * v3;
            }
        }
    }

    // merge 4 ksub waves via LDS overlay (aliases everything), write partial
    __syncthreads();
    if (ksub) {
#pragma unroll
        for (int qq = 0; qq < 2; ++qq) {
            float* p = &smem[(((ksub - 1) * 16 + qg * 2 + qq) * 8 + h) * 12];
            *(float4*)p       = make_float4(oacc[qq][0].x, oacc[qq][0].y, oacc[qq][1].x, oacc[qq][1].y);
            *(float4*)(p + 4) = make_float4(oacc[qq][2].x, oacc[qq][2].y, oacc[qq][3].x, oacc[qq][3].y);
            p[8] = lsum[qq];
        }
    }
    __syncthreads();
    if (ksub == 0) {
#pragma unroll
        for (int qq = 0; qq < 2; ++qq) {
            int q = qg * 2 + qq;
            float ov[8] = { oacc[qq][0].x, oacc[qq][0].y, oacc[qq][1].x, oacc[qq][1].y,
                            oacc[qq][2].x, oacc[qq][2].y, oacc[qq][3].x, oacc[qq][3].y };
            float lq = lsum[qq];
#pragma unroll
            for (int m = 0; m < 3; ++m) {
                const float* p = &smem[((m * 16 + q) * 8 + h) * 12];
                float4 m0 = *(const float4*)p, m1 = *(const float4*)(p + 4);
                ov[0] += m0.x; ov[1] += m0.y; ov[2] += m0.z; ov[3] += m0.w;
                ov[4] += m1.x; ov[5] += m1.y; ov[6] += m1.z; ov[7] += m1.w;
                lq += p[8];
            }
            float* pp = ws + OFF_PART + (z * LEN + q0 + q) * 768 + (h * 8 + ks) * 12;
            *(float4*)(pp)     = make_float4(ov[0], ov[1], ov[2], ov[3]);
            *(float4*)(pp + 4) = make_float4(ov[4], ov[5], ov[6], ov[7]);
            *(float4*)(pp + 8) = make_float4(lq, 0.f, 0.f, 0.f);
        }
    }
}

// ---- fused: partial-merge + Wo + LN + FFN + LN + next-QKV (+head on last) ----
// 4 rows per 256-thread block: wave w = row w for wave-per-row phases;
// FFN/head hidden and Q2/KB/VB share weight reads across rows.
// grid (bx=512, kind=2).
__global__ __launch_bounds__(256) void k_fuse(int blk, float* ws, void* out_raw) {
    __shared__ float raw[3072];       // 4 rows x 768
    __shared__ float xo[4][64];
    __shared__ float xs[4][64];
    __shared__ float hs[4][128];
    __shared__ float xn[4][64];
    __shared__ int sflag;
    const int bx = blockIdx.x, kind = blockIdx.y, t = threadIdx.x;
    const int r0 = bx * 4;            // rows r0..r0+3 (same b: 1024 % 4 == 0)
    const int b = r0 >> 10, row0 = r0 & 1023;
    const int z = kind * 2 + b;
    const int w = t >> 6, tt = t & 63;   // wave w handles row r0+w in per-row phases
    float* io = ws + (kind == 0 ? OFF_QVS : OFF_KVS);

    const float* pbase = ws + OFF_PART + (z * LEN + row0) * 768;  // 4 rows contiguous
    for (int i = t; i < 768; i += 256) *(float4*)&raw[i * 4] = *(const float4*)&pbase[i * 4];
    __syncthreads();

    // merge 8 K-split partials per (row=w, h, d): plain sums (256 lanes = 4x64)
    {
        int h = tt >> 3, d = tt & 7;
        const float* rw = raw + w * 768;
        float L = 0.f, o = 0.f;
#pragma unroll
        for (int k2 = 0; k2 < 8; ++k2) {
            L += rw[(h * 8 + k2) * 12 + 8];
            o += rw[(h * 8 + k2) * 12 + d];
        }
        xo[w][tt] = o / L;
    }
    __syncthreads();

    // Wo projection + residual + LN; wave per row
    {
        const float* Wo = ws + I_WO + blk * 4096;
        float acc = ws[I_BO + blk * 64 + tt];
#pragma unroll 8
        for (int j = 0; j < 64; ++j) acc += xo[w][j] * Wo[j * 64 + tt];
        acc += io[(r0 + w) * 64 + tt];
        float s = acc, ss2 = acc * acc;
#pragma unroll
        for (int off = 1; off < 64; off <<= 1) { s += __shfl_xor(s, off); ss2 += __shfl_xor(ss2, off); }
        float mu_ = s * (1.f / 64.f);
        float var_ = ss2 * (1.f / 64.f) - mu_ * mu_;
        float rs_ = rsqrtf(fmaxf(var_, 0.f) + 1e-6f);
        xs[w][tt] = (acc - mu_) * rs_ * ws[I_NS + blk * 64 + tt] + ws[I_NB + blk * 64 + tt];
    }
    __syncthreads();

    // FFN hidden: col = t&127, row pair rp = t>>7 (weight read shared 2x)
    {
        int col = t & 127, rp = (t >> 7) * 2;
        const float* W1 = ws + I_FW1 + blk * 8192;
        float a0 = ws[I_FB1 + blk * 128 + col], a1 = a0;
#pragma unroll 8
        for (int k = 0; k < 64; ++k) {
            float wv = W1[k * 128 + col];
            a0 += xs[rp][k] * wv;
            a1 += xs[rp + 1][k] * wv;
        }
        hs[rp][col]     = fmaxf(a0, 0.f);
        hs[rp + 1][col] = fmaxf(a1, 0.f);
    }
    __syncthreads();

    // FFN out + residual + LN -> new layer state; wave per row
    {
        const float* W2 = ws + I_FW2 + blk * 8192;
        float a2 = ws[I_FB2 + blk * 64 + tt];
#pragma unroll 8
        for (int k = 0; k < 128; ++k) a2 += hs[w][k] * W2[k * 64 + tt];
        a2 += xs[w][tt];
        float s = a2, ss2 = a2 * a2;
#pragma unroll
        for (int off = 1; off < 64; off <<= 1) { s += __shfl_xor(s, off); ss2 += __shfl_xor(ss2, off); }
        float mu_ = s * (1.f / 64.f);
        float var_ = ss2 * (1.f / 64.f) - mu_ * mu_;
        float rs_ = rsqrtf(fmaxf(var_, 0.f) + 1e-6f);
        float outv = (a2 - mu_) * rs_ * ws[I_NS + blk * 64 + tt] + ws[I_NB + blk * 64 + tt];
        io[(r0 + w) * 64 + tt] = outv;
        xn[w][tt] = outv;
    }
    __syncthreads();

    if (blk < 5) {   // next-layer QKV projection
        const int nb_ = blk + 1;
        if (kind == 0) {
            // Q1: wave per row
            const float* W = ws + I_WQ + nb_ * 4096;
            float acc = ws[I_BQ + nb_ * 64 + tt];
#pragma unroll 8
            for (int k = 0; k < 64; ++k) acc += xn[w][k] * W[k * 64 + tt];
            ws[OFF_Q1 + (r0 + w) * 64 + tt] = acc;
        } else {
            if (w < 2) {
                // w0: Q2 all 4 rows; w1: KB all 4 rows (weight read shared 4x)
                const float* W  = ws + (w == 0 ? I_WQ : I_WK) + nb_ * 4096;
                const float* bbp = ws + (w == 0 ? I_BQ : I_BK) + nb_ * 64;
                float* dst = ws + (w == 0 ? OFF_Q2 : OFF_KB);
                float a0 = bbp[tt], a1 = a0, a2 = a0, a3 = a0;
#pragma unroll 8
                for (int k = 0; k < 64; ++k) {
                    float wv = W[k * 64 + tt];
                    a0 += xn[0][k] * wv;
                    a1 += xn[1][k] * wv;
                    a2 += xn[2][k] * wv;
                    a3 += xn[3][k] * wv;
                }
                dst[(r0 + 0) * 64 + tt] = a0;
                dst[(r0 + 1) * 64 + tt] = a1;
                dst[(r0 + 2) * 64 + tt] = a2;
                dst[(r0 + 3) * 64 + tt] = a3;
            } else {
                // w2: VB rows 0-1; w3: VB rows 2-3 (weight read shared 2x)
                int rb = (w - 2) * 2;
                const float* Wv = ws + I_WV + nb_ * 4096;
                float a0 = ws[I_BV + nb_ * 64 + tt], a1 = a0;
#pragma unroll 8
                for (int k = 0; k < 64; ++k) {
                    float wv = Wv[k * 64 + tt];
                    a0 += xn[rb][k] * wv;
                    a1 += xn[rb + 1][k] * wv;
                }
                ws[OFF_VB + (r0 + rb) * 64 + tt]     = a0;
                ws[OFF_VB + (r0 + rb + 1) * 64 + tt] = a1;
            }
        }
    } else if (kind == 0) {
        // ---- inline head for rows r0..r0+3 (xn holds final qvs) ----
        if (t == 0) sflag = ((const int*)(ws + OFF_FLAG))[0];
        // final LN per row (wave per row), into xo
        {
            float v = xn[w][tt];
            float s = v, ss2 = v * v;
#pragma unroll
            for (int off = 1; off < 64; off <<= 1) { s += __shfl_xor(s, off); ss2 += __shfl_xor(ss2, off); }
            float mu_ = s * (1.f / 64.f);
            float var_ = ss2 * (1.f / 64.f) - mu_ * mu_;
            float rs_ = rsqrtf(fmaxf(var_, 0.f) + 1e-6f);
            xo[w][tt] = (v - mu_) * rs_ * ws[I_FNS + tt] + ws[I_FNB + tt];
        }
        __syncthreads();
        // head hidden: col = t&127, row pair rp = t>>7 (weight shared 2x)
        {
            int col = t & 127, rp = (t >> 7) * 2;
            float a0 = ws[I_HB1 + col], a1 = a0;
#pragma unroll 8
            for (int k = 0; k < 64; ++k) {
                float wv = ws[I_HW1 + k * 128 + col];
                a0 += xo[rp][k] * wv;
                a1 += xo[rp + 1][k] * wv;
            }
            hs[rp][col]     = fmaxf(a0, 0.f);
            hs[rp + 1][col] = fmaxf(a1, 0.f);
        }
        __syncthreads();
        if (t < 8) {
            int row = t >> 1, c = t & 1;
            float a = ws[I_HB2 + c];
            for (int j = 0; j < 128; ++j) a += hs[row][j] * ws[I_HW2 + j * 2 + c];
            float v = (c == 0) ? a : __expf(a * 0.5f);
            int r = r0 + row;
            int idx = (c == 0) ? r : (N2 + r);
            if (sflag) ((bf16*)out_raw)[idx] = __float2bfloat16(v);
            else       ((float*)out_raw)[idx] = v;
        }
    }
}

extern "C" void kernel_launch(void* const* d_in, const int* in_sizes, int n_in,
                              void* d_out, int out_size, void* d_ws, size_t ws_size,
                              hipStream_t stream) {
    float* ws = (float*)d_ws;

    InPtrs ptrs;
    for (int i = 0; i < 32; ++i) ptrs.p[i] = d_in[i];

    k_pre<<<262, 256, 0, stream>>>(ptrs, ws);                 // cvt + flag + pw tables
    k_emq<<<1024, 256, 0, stream>>>(ws);                      // embed + layer-0 QKV (2 rows/blk)
    for (int i = 0; i < 6; ++i) {
        k_attn<<<dim3(64, 8, 4), 256, 0, stream>>>(i, ws);
        k_fuse<<<dim3(512, 2), 256, 0, stream>>>(i, ws, d_out);  // 4 rows/blk; head on i=5
    }
}

// Round 17
// 430.320 us; speedup vs baseline: 1.0176x; 1.0176x over previous
//
#include <hip/hip_runtime.h>
#include <hip/hip_bf16.h>

typedef __hip_bfloat16 bf16;
typedef float v2f __attribute__((ext_vector_type(2)));

#define LEN 1024
#define N2 2048            // B * L rows
#define SCALE_L2E 0.5100697918f   // (1/sqrt(8)) * log2(e)

// ---- converted-input float offsets in ws ----
#define I_SCTX   0
#define I_FCTX   4096
#define I_STEST  6144
#define I_OBS    10240
#define I_EW1    10248
#define I_EB1    12040
#define I_EW2    12296
#define I_EB2    28680
#define I_WQ     28744
#define I_BQ     53320
#define I_WK     53704
#define I_BK     78280
#define I_WV     78664
#define I_BV     103240
#define I_WO     103624
#define I_BO     128200
#define I_FW1    128584
#define I_FB1    177736
#define I_FW2    178504
#define I_FB2    227656
#define I_BW1    228040
#define I_BB1    228136
#define I_BW2    228232
#define I_BB2    229000
#define I_NS     229048
#define I_NB     229432
#define I_FNS    229816
#define I_FNB    229880
#define I_HW1    229944
#define I_HB1    238136
#define I_HW2    238264
#define I_HB2    238520

#define OFF_FLAG 240000
#define OFF_PW   240256    // 6 layers x 288 floats: [17][8] (slope,inter)*log2e + 16 sorted bps
#define OFF_QVS  262144
#define OFF_KVS  393216
#define OFF_Q1   524288
#define OFF_Q2   655360
#define OFF_KB   786432
#define OFF_VB   917504
#define OFF_PART 1048576   // partials: [z=4][row=1024][h=8][ks=8][12] floats (row stride 768)

__constant__ int C_OFFS[33] = {
    0, 4096, 6144, 10240, 10248, 12040, 12296, 28680, 28744, 53320, 53704,
    78280, 78664, 103240, 103624, 128200, 128584, 177736, 178504, 227656,
    228040, 228136, 228232, 229000, 229048, 229432, 229816, 229880, 229944,
    238136, 238264, 238520, 238522 };

struct InPtrs { const void* p[32]; };

__device__ __forceinline__ int get_isbf(const void* ns) {
    return (*(const unsigned*)ns == 0x3F803F80u) ? 1 : 0;
}

// ---- merged prologue: input conversion (blocks 0..255) + flag + piecewise
// bias tables (blocks 256..261). pwf reads raw inputs -> no ordering dep.
__global__ __launch_bounds__(256) void k_pre(InPtrs ptrs, float* ws) {
    const int bid = blockIdx.x, t = threadIdx.x;
    const int isbf = get_isbf(ptrs.p[24]);
    if (bid < 256) {
        const int i = bid & 31, sub = bid >> 5;
        const int o0 = C_OFFS[i], n = C_OFFS[i + 1] - o0;
        const void* src = ptrs.p[i];
        for (int j = sub * 256 + t; j < n; j += 8 * 256) {
            float v = isbf ? __bfloat162float(((const bf16*)src)[j])
                           : ((const float*)src)[j];
            ws[o0 + j] = v;
        }
        return;
    }
    // ---- piecewise tables for layer L ----
    const int L = bid - 256;
    __shared__ float w1s[16], b1s[16], bps[16];
    __shared__ int rnk[16];
    auto cv = [&](const void* p, int idx) -> float {
        return isbf ? __bfloat162float(((const bf16*)p)[idx]) : ((const float*)p)[idx];
    };
    if (t == 0 && L == 0) ((int*)(ws + OFF_FLAG))[0] = isbf;
    if (t < 16) {
        float w = cv(ptrs.p[20], L * 16 + t), b0 = cv(ptrs.p[21], L * 16 + t);
        w1s[t] = w; b1s[t] = b0;
        bps[t] = (w != 0.f) ? (-b0 / w) : 1e30f;
    }
    __syncthreads();
    if (t < 16) {
        float me = bps[t]; int r = 0;
        for (int j = 0; j < 16; ++j) {
            float o = bps[j];
            if (o < me || (o == me && j < t)) ++r;
        }
        rnk[t] = r;
    }
    __syncthreads();
    if (t < 16) ws[OFF_PW + L * 288 + 272 + rnk[t]] = bps[t];
    if (t < 136) {
        int s = t >> 3, h = t & 7;
        float slope = 0.f, inter = cv(ptrs.p[23], L * 8 + h);
        for (int j = 0; j < 16; ++j) {
            float w = w1s[j];
            bool act = (w > 0.f) ? (rnk[j] < s)
                     : (w < 0.f) ? (rnk[j] >= s)
                                 : (b1s[j] > 0.f);
            if (act) {
                float w2v = cv(ptrs.p[22], L * 128 + j * 8 + h);
                slope += w * w2v;
                inter += b1s[j] * w2v;
            }
        }
        const float LOG2E = 1.4426950408889634f;
        ws[OFF_PW + L * 288 + (s * 8 + h) * 2]     = slope * LOG2E;
        ws[OFF_PW + L * 288 + (s * 8 + h) * 2 + 1] = inter * LOG2E;
    }
}

// ---- merged embed MLP + layer-0 QKV; 2 rows per block (4 MLP instances
// share every weight read). grid 1024 x 256. Per-row math order unchanged.
__global__ __launch_bounds__(256) void k_emq(float* ws) {
    __shared__ float hbuf[4][256];    // c = lr*2 + which (0=ctx, 1=test)
    __shared__ float red[4][256];
    __shared__ float xs[4][64];
    const int r0 = blockIdx.x * 2, t = threadIdx.x;

    float in_[4][7];
#pragma unroll
    for (int lr = 0; lr < 2; ++lr) {
        int r = r0 + lr;
        const float* obc = ws + I_OBS + 4;
        const float* obu = ws + I_OBS;
        float* ic = in_[lr * 2]; float* it = in_[lr * 2 + 1];
        ic[0] = obc[0]; ic[1] = obc[1]; ic[2] = obc[2]; ic[3] = obc[3];
        it[0] = obu[0]; it[1] = obu[1]; it[2] = obu[2]; it[3] = obu[3];
        ic[4] = ws[I_SCTX + r * 2]; ic[5] = ws[I_SCTX + r * 2 + 1];
        it[4] = ws[I_STEST + r * 2]; it[5] = ws[I_STEST + r * 2 + 1];
        ic[6] = ws[I_FCTX + r]; it[6] = 0.f;
    }
    float a[4];
    {
        float b1v = ws[I_EB1 + t];
        a[0] = a[1] = a[2] = a[3] = b1v;
    }
#pragma unroll
    for (int i = 0; i < 7; ++i) {
        float w = ws[I_EW1 + i * 256 + t];
#pragma unroll
        for (int c = 0; c < 4; ++c) a[c] += in_[c][i] * w;
    }
#pragma unroll
    for (int c = 0; c < 4; ++c) hbuf[c][t] = fmaxf(a[c], 0.f);
    __syncthreads();

    {
        int d = t & 63, p = t >> 6;
        float s2[4] = {0.f, 0.f, 0.f, 0.f};
#pragma unroll 8
        for (int j = p * 64; j < p * 64 + 64; ++j) {
            float w = ws[I_EW2 + j * 64 + d];
#pragma unroll
            for (int c = 0; c < 4; ++c) s2[c] += hbuf[c][j] * w;
        }
#pragma unroll
        for (int c = 0; c < 4; ++c) red[c][t] = s2[c];
    }
    __syncthreads();
    {
        int c = t >> 6, d2 = t & 63;
        float o = red[c][d2] + red[c][64 + d2] + red[c][128 + d2]
                + red[c][192 + d2] + ws[I_EB2 + d2];
        int lr = c >> 1, which = c & 1; int r = r0 + lr;
        if (which == 0) ws[OFF_KVS + r * 64 + d2] = o;
        else            ws[OFF_QVS + r * 64 + d2] = o;
        xs[c][d2] = o;
    }
    __syncthreads();

    // layer-0 QKV: wave o4: 0=Q1(test), 1=Q2(ctx), 2=KB(ctx), 3=VB(ctx);
    // each wave projects BOTH rows (weight read shared 2x)
    {
        int o4 = t >> 6, d = t & 63;
        const float* W; const float* bbp; float* dst; int whichx;
        if (o4 == 0)      { W = ws + I_WQ; bbp = ws + I_BQ; dst = ws + OFF_Q1; whichx = 1; }
        else if (o4 == 1) { W = ws + I_WQ; bbp = ws + I_BQ; dst = ws + OFF_Q2; whichx = 0; }
        else if (o4 == 2) { W = ws + I_WK; bbp = ws + I_BK; dst = ws + OFF_KB; whichx = 0; }
        else              { W = ws + I_WV; bbp = ws + I_BV; dst = ws + OFF_VB; whichx = 0; }
        float a0 = bbp[d], a1 = a0;
#pragma unroll 8
        for (int k = 0; k < 64; ++k) {
            float w = W[k * 64 + d];
            a0 += xs[whichx][k] * w;
            a1 += xs[2 + whichx][k] * w;
        }
        dst[r0 * 64 + d]       = a0;
        dst[(r0 + 1) * 64 + d] = a1;
    }
}

// ---- attention: wave-private tiles, NO per-tile barriers (R13/R15 best;
// final configuration — R16's pw-stride pad was a null result, reverted).
// Each wave w (= ksub) owns key rows [4w, 4w+4) of every 16-key tile: it
// stages its own K/V rows, computes the bias rows for ITS keys x all 16
// queries, and the inner loop reads only its own rows. 3 barriers per block.
// grid (qt=64, ks=8, z=4); launch bounds (256,4) (proven: forcing 8 waves/EU
// collapses the allocator to 32 VGPR + 394 MB spill).
__global__ __launch_bounds__(256, 4) void k_attn(int blk, float* ws) {
    __shared__ float smem[4608];            // 18432 B
    float* Ks  = smem;                      // 16 x 68
    float* Vs  = smem + 1088;               // 16 x 68
    float* bbf = smem + 2176;               // bias [16][132] = 2112
    v2f* pw = (v2f*)(smem + 4288);          // 272 floats

    const int t = threadIdx.x;
    const int qt = blockIdx.x, ks = blockIdx.y, z = blockIdx.z;
    const int b = z & 1, kind = z >> 1;
    const int q0 = qt * 16;
    const float* Qbuf = ws + (kind == 0 ? OFF_Q1 : OFF_Q2);
    const float* Kbuf = ws + OFF_KB;
    const float* Vbuf = ws + OFF_VB;
    const float* sq_src = ws + (kind == 0 ? I_STEST : I_SCTX);
    const float* sk_src = ws + I_SCTX;
    const float* pwg = ws + OFF_PW + blk * 288;   // uniform -> scalar loads

    float bp[16];
#pragma unroll
    for (int j = 0; j < 16; ++j) bp[j] = pwg[272 + j];

    if (t < 136) pw[t] = (v2f){ pwg[t * 2], pwg[t * 2 + 1] };

    const int h    = t & 7;         // head (inner loop)
    const int qg   = (t >> 3) & 7;  // query pair (qg*2, qg*2+1) (inner loop)
    const int ksub = t >> 6;        // wave id == key quartet [4*ksub, +4)

    // Q fragments for 2 queries, resident in registers
    v2f qf[2][4];
#pragma unroll
    for (int qq = 0; qq < 2; ++qq) {
        const float* qp = Qbuf + (b * LEN + q0 + qg * 2 + qq) * 64 + h * 8;
        float4 qa = *(const float4*)qp;
        float4 qb = *(const float4*)(qp + 4);
        qf[qq][0] = (v2f){qa.x, qa.y}; qf[qq][1] = (v2f){qa.z, qa.w};
        qf[qq][2] = (v2f){qb.x, qb.y}; qf[qq][3] = (v2f){qb.z, qb.w};
    }
    // bias-phase coords: this thread handles (k = 4*ksub + (t&3), q = (t>>2)&15)
    const int kp = ksub * 4 + (t & 3);      // key row (wave-private quartet)
    const int qs = (t >> 2) & 15;           // query for bias
    float sqx, sqy;
    {
        const float* sp = sq_src + (b * LEN + q0 + qs) * 2;
        sqx = sp[0]; sqy = sp[1];
    }

    float lsum[2] = {0.f, 0.f};
    v2f oacc[2][4] = {};

    const int kt0 = ks * 8, kt1 = kt0 + 8;   // tiles of 16 keys
    const int kr = t >> 4, jc = (t & 15) * 4;   // staging coords (kr in-wave)

    // prologue: prefetch tile kt0 (K/V fragments AND key coords)
    float4 ka, va;
    float2 kc_pf;
    {
        const float* ksrc = Kbuf + (b * LEN + kt0 * 16 + kr) * 64 + jc;
        const float* vsrc = Vbuf + (b * LEN + kt0 * 16 + kr) * 64 + jc;
        ka = *(const float4*)ksrc;
        va = *(const float4*)vsrc;
        kc_pf = *(const float2*)(sk_src + (b * LEN + kt0 * 16 + kp) * 2);
    }

    __syncthreads();                  // pw table visible to all waves

    for (int kt = kt0; kt < kt1; ++kt) {
        // stage this wave's K/V rows (within-wave write->read only)
        *(float4*)&Ks[kr * 68 + jc] = ka;
        *(float4*)&Vs[kr * 68 + jc] = va;
        {   // bias precompute for wave-private keys: (kp, qs) pair
            float dx0 = sqx - kc_pf.x, dy0 = sqy - kc_pf.y;
            float d0 = dx0 * dx0 + dy0 * dy0;
            int s0 = 0;
#pragma unroll
            for (int j = 0; j < 16; ++j) s0 += (d0 > bp[j]);
            const float* p0 = (const float*)(pw + s0 * 8);   // 16 floats: sl,in x8
            float* bd0 = &bbf[kp * 132 + qs * 8];
            float4 a0 = *(const float4*)p0,       a1 = *(const float4*)(p0 + 4);
            float4 a2 = *(const float4*)(p0 + 8), a3 = *(const float4*)(p0 + 12);
            *(float4*)bd0       = make_float4(fmaf(a0.x, d0, a0.y), fmaf(a0.z, d0, a0.w),
                                              fmaf(a1.x, d0, a1.y), fmaf(a1.z, d0, a1.w));
            *(float4*)(bd0 + 4) = make_float4(fmaf(a2.x, d0, a2.y), fmaf(a2.z, d0, a2.w),
                                              fmaf(a3.x, d0, a3.y), fmaf(a3.z, d0, a3.w));
        }

        // prefetch next tile (K/V + kc; latency hides under compute below)
        if (kt + 1 < kt1) {
            const float* ksrc = Kbuf + (b * LEN + (kt + 1) * 16 + kr) * 64 + jc;
            const float* vsrc = Vbuf + (b * LEN + (kt + 1) * 16 + kr) * 64 + jc;
            ka = *(const float4*)ksrc;
            va = *(const float4*)vsrc;
            kc_pf = *(const float2*)(sk_src + (b * LEN + (kt + 1) * 16 + kp) * 2);
        }

        // inner: 4 wave-private keys; K/V frags broadcast 8-way, 2 queries each
        const float* Kb = &Ks[(ksub * 4) * 68 + h * 8];
        const float* Vb = &Vs[(ksub * 4) * 68 + h * 8];
        const float* Bb = &bbf[(ksub * 4) * 132 + qg * 16 + h];
#pragma unroll
        for (int k4 = 0; k4 < 4; ++k4) {
            const v2f* kf = (const v2f*)(Kb + k4 * 68);
            v2f k0 = kf[0], k1 = kf[1], k2v = kf[2], k3 = kf[3];
            const v2f* vf = (const v2f*)(Vb + k4 * 68);
            v2f v0 = vf[0], v1 = vf[1], v2v = vf[2], v3 = vf[3];
#pragma unroll
            for (int qq = 0; qq < 2; ++qq) {
                float bv = Bb[k4 * 132 + qq * 8];
                v2f a = qf[qq][0] * k0;
                a += qf[qq][1] * k1;
                a += qf[qq][2] * k2v;
                a += qf[qq][3] * k3;
                float sv = fmaf(a.x + a.y, SCALE_L2E, bv);
                float p = exp2f(sv);
                lsum[qq] += p;
                v2f pp = (v2f){p, p};
                oacc[qq][0] += pp * v0;
                oacc[qq][1] += pp * v1;
                oacc[qq][2] += pp * v2v;
                oacc[qq][3] += pp * v3;
            }
        }
    }

    // merge 4 ksub waves via LDS overlay (aliases everything), write partial
    __syncthreads();
    if (ksub) {
#pragma unroll
        for (int qq = 0; qq < 2; ++qq) {
            float* p = &smem[(((ksub - 1) * 16 + qg * 2 + qq) * 8 + h) * 12];
            *(float4*)p       = make_float4(oacc[qq][0].x, oacc[qq][0].y, oacc[qq][1].x, oacc[qq][1].y);
            *(float4*)(p + 4) = make_float4(oacc[qq][2].x, oacc[qq][2].y, oacc[qq][3].x, oacc[qq][3].y);
            p[8] = lsum[qq];
        }
    }
    __syncthreads();
    if (ksub == 0) {
#pragma unroll
        for (int qq = 0; qq < 2; ++qq) {
            int q = qg * 2 + qq;
            float ov[8] = { oacc[qq][0].x, oacc[qq][0].y, oacc[qq][1].x, oacc[qq][1].y,
                            oacc[qq][2].x, oacc[qq][2].y, oacc[qq][3].x, oacc[qq][3].y };
            float lq = lsum[qq];
#pragma unroll
            for (int m = 0; m < 3; ++m) {
                const float* p = &smem[((m * 16 + q) * 8 + h) * 12];
                float4 m0 = *(const float4*)p, m1 = *(const float4*)(p + 4);
                ov[0] += m0.x; ov[1] += m0.y; ov[2] += m0.z; ov[3] += m0.w;
                ov[4] += m1.x; ov[5] += m1.y; ov[6] += m1.z; ov[7] += m1.w;
                lq += p[8];
            }
            float* pp = ws + OFF_PART + (z * LEN + q0 + q) * 768 + (h * 8 + ks) * 12;
            *(float4*)(pp)     = make_float4(ov[0], ov[1], ov[2], ov[3]);
            *(float4*)(pp + 4) = make_float4(ov[4], ov[5], ov[6], ov[7]);
            *(float4*)(pp + 8) = make_float4(lq, 0.f, 0.f, 0.f);
        }
    }
}

// ---- fused: partial-merge + Wo + LN + FFN + LN + next-QKV (+head on last) ----
// 4 rows per 256-thread block: wave w = row w for wave-per-row phases;
// FFN/head hidden and Q2/KB/VB share weight reads across rows.
// grid (bx=512, kind=2).
__global__ __launch_bounds__(256) void k_fuse(int blk, float* ws, void* out_raw) {
    __shared__ float raw[3072];       // 4 rows x 768
    __shared__ float xo[4][64];
    __shared__ float xs[4][64];
    __shared__ float hs[4][128];
    __shared__ float xn[4][64];
    __shared__ int sflag;
    const int bx = blockIdx.x, kind = blockIdx.y, t = threadIdx.x;
    const int r0 = bx * 4;            // rows r0..r0+3 (same b: 1024 % 4 == 0)
    const int b = r0 >> 10, row0 = r0 & 1023;
    const int z = kind * 2 + b;
    const int w = t >> 6, tt = t & 63;   // wave w handles row r0+w in per-row phases
    float* io = ws + (kind == 0 ? OFF_QVS : OFF_KVS);

    const float* pbase = ws + OFF_PART + (z * LEN + row0) * 768;  // 4 rows contiguous
    for (int i = t; i < 768; i += 256) *(float4*)&raw[i * 4] = *(const float4*)&pbase[i * 4];
    __syncthreads();

    // merge 8 K-split partials per (row=w, h, d): plain sums (256 lanes = 4x64)
    {
        int h = tt >> 3, d = tt & 7;
        const float* rw = raw + w * 768;
        float L = 0.f, o = 0.f;
#pragma unroll
        for (int k2 = 0; k2 < 8; ++k2) {
            L += rw[(h * 8 + k2) * 12 + 8];
            o += rw[(h * 8 + k2) * 12 + d];
        }
        xo[w][tt] = o / L;
    }
    __syncthreads();

    // Wo projection + residual + LN; wave per row
    {
        const float* Wo = ws + I_WO + blk * 4096;
        float acc = ws[I_BO + blk * 64 + tt];
#pragma unroll 8
        for (int j = 0; j < 64; ++j) acc += xo[w][j] * Wo[j * 64 + tt];
        acc += io[(r0 + w) * 64 + tt];
        float s = acc, ss2 = acc * acc;
#pragma unroll
        for (int off = 1; off < 64; off <<= 1) { s += __shfl_xor(s, off); ss2 += __shfl_xor(ss2, off); }
        float mu_ = s * (1.f / 64.f);
        float var_ = ss2 * (1.f / 64.f) - mu_ * mu_;
        float rs_ = rsqrtf(fmaxf(var_, 0.f) + 1e-6f);
        xs[w][tt] = (acc - mu_) * rs_ * ws[I_NS + blk * 64 + tt] + ws[I_NB + blk * 64 + tt];
    }
    __syncthreads();

    // FFN hidden: col = t&127, row pair rp = t>>7 (weight read shared 2x)
    {
        int col = t & 127, rp = (t >> 7) * 2;
        const float* W1 = ws + I_FW1 + blk * 8192;
        float a0 = ws[I_FB1 + blk * 128 + col], a1 = a0;
#pragma unroll 8
        for (int k = 0; k < 64; ++k) {
            float wv = W1[k * 128 + col];
            a0 += xs[rp][k] * wv;
            a1 += xs[rp + 1][k] * wv;
        }
        hs[rp][col]     = fmaxf(a0, 0.f);
        hs[rp + 1][col] = fmaxf(a1, 0.f);
    }
    __syncthreads();

    // FFN out + residual + LN -> new layer state; wave per row
    {
        const float* W2 = ws + I_FW2 + blk * 8192;
        float a2 = ws[I_FB2 + blk * 64 + tt];
#pragma unroll 8
        for (int k = 0; k < 128; ++k) a2 += hs[w][k] * W2[k * 64 + tt];
        a2 += xs[w][tt];
        float s = a2, ss2 = a2 * a2;
#pragma unroll
        for (int off = 1; off < 64; off <<= 1) { s += __shfl_xor(s, off); ss2 += __shfl_xor(ss2, off); }
        float mu_ = s * (1.f / 64.f);
        float var_ = ss2 * (1.f / 64.f) - mu_ * mu_;
        float rs_ = rsqrtf(fmaxf(var_, 0.f) + 1e-6f);
        float outv = (a2 - mu_) * rs_ * ws[I_NS + blk * 64 + tt] + ws[I_NB + blk * 64 + tt];
        io[(r0 + w) * 64 + tt] = outv;
        xn[w][tt] = outv;
    }
    __syncthreads();

    if (blk < 5) {   // next-layer QKV projection
        const int nb_ = blk + 1;
        if (kind == 0) {
            // Q1: wave per row
            const float* W = ws + I_WQ + nb_ * 4096;
            float acc = ws[I_BQ + nb_ * 64 + tt];
#pragma unroll 8
            for (int k = 0; k < 64; ++k) acc += xn[w][k] * W[k * 64 + tt];
            ws[OFF_Q1 + (r0 + w) * 64 + tt] = acc;
        } else {
            if (w < 2) {
                // w0: Q2 all 4 rows; w1: KB all 4 rows (weight read shared 4x)
                const float* W  = ws + (w == 0 ? I_WQ : I_WK) + nb_ * 4096;
                const float* bbp = ws + (w == 0 ? I_BQ : I_BK) + nb_ * 64;
                float* dst = ws + (w == 0 ? OFF_Q2 : OFF_KB);
                float a0 = bbp[tt], a1 = a0, a2 = a0, a3 = a0;
#pragma unroll 8
                for (int k = 0; k < 64; ++k) {
                    float wv = W[k * 64 + tt];
                    a0 += xn[0][k] * wv;
                    a1 += xn[1][k] * wv;
                    a2 += xn[2][k] * wv;
                    a3 += xn[3][k] * wv;
                }
                dst[(r0 + 0) * 64 + tt] = a0;
                dst[(r0 + 1) * 64 + tt] = a1;
                dst[(r0 + 2) * 64 + tt] = a2;
                dst[(r0 + 3) * 64 + tt] = a3;
            } else {
                // w2: VB rows 0-1; w3: VB rows 2-3 (weight read shared 2x)
                int rb = (w - 2) * 2;
                const float* Wv = ws + I_WV + nb_ * 4096;
                float a0 = ws[I_BV + nb_ * 64 + tt], a1 = a0;
#pragma unroll 8
                for (int k = 0; k < 64; ++k) {
                    float wv = Wv[k * 64 + tt];
                    a0 += xn[rb][k] * wv;
                    a1 += xn[rb + 1][k] * wv;
                }
                ws[OFF_VB + (r0 + rb) * 64 + tt]     = a0;
                ws[OFF_VB + (r0 + rb + 1) * 64 + tt] = a1;
            }
        }
    } else if (kind == 0) {
        // ---- inline head for rows r0..r0+3 (xn holds final qvs) ----
        if (t == 0) sflag = ((const int*)(ws + OFF_FLAG))[0];
        // final LN per row (wave per row), into xo
        {
            float v = xn[w][tt];
            float s = v, ss2 = v * v;
#pragma unroll
            for (int off = 1; off < 64; off <<= 1) { s += __shfl_xor(s, off); ss2 += __shfl_xor(ss2, off); }
            float mu_ = s * (1.f / 64.f);
            float var_ = ss2 * (1.f / 64.f) - mu_ * mu_;
            float rs_ = rsqrtf(fmaxf(var_, 0.f) + 1e-6f);
            xo[w][tt] = (v - mu_) * rs_ * ws[I_FNS + tt] + ws[I_FNB + tt];
        }
        __syncthreads();
        // head hidden: col = t&127, row pair rp = t>>7 (weight shared 2x)
        {
            int col = t & 127, rp = (t >> 7) * 2;
            float a0 = ws[I_HB1 + col], a1 = a0;
#pragma unroll 8
            for (int k = 0; k < 64; ++k) {
                float wv = ws[I_HW1 + k * 128 + col];
                a0 += xo[rp][k] * wv;
                a1 += xo[rp + 1][k] * wv;
            }
            hs[rp][col]     = fmaxf(a0, 0.f);
            hs[rp + 1][col] = fmaxf(a1, 0.f);
        }
        __syncthreads();
        if (t < 8) {
            int row = t >> 1, c = t & 1;
            float a = ws[I_HB2 + c];
            for (int j = 0; j < 128; ++j) a += hs[row][j] * ws[I_HW2 + j * 2 + c];
            float v = (c == 0) ? a : __expf(a * 0.5f);
            int r = r0 + row;
            int idx = (c == 0) ? r : (N2 + r);
            if (sflag) ((bf16*)out_raw)[idx] = __float2bfloat16(v);
            else       ((float*)out_raw)[idx] = v;
        }
    }
}

extern "C" void kernel_launch(void* const* d_in, const int* in_sizes, int n_in,
                              void* d_out, int out_size, void* d_ws, size_t ws_size,
                              hipStream_t stream) {
    float* ws = (float*)d_ws;

    InPtrs ptrs;
    for (int i = 0; i < 32; ++i) ptrs.p[i] = d_in[i];

    k_pre<<<262, 256, 0, stream>>>(ptrs, ws);                 // cvt + flag + pw tables
    k_emq<<<1024, 256, 0, stream>>>(ws);                      // embed + layer-0 QKV (2 rows/blk)
    for (int i = 0; i < 6; ++i) {
        k_attn<<<dim3(64, 8, 4), 256, 0, stream>>>(i, ws);
        k_fuse<<<dim3(512, 2), 256, 0, stream>>>(i, ws, d_out);  // 4 rows/blk; head on i=5
    }
}